// Round 11
// baseline (85.245 us; speedup 1.0000x reference)
//
#include <hip/hip_runtime.h>

#define HH 1024
#define WW 1024
#define BB 8

typedef float v4f __attribute__((ext_vector_type(4)));

__global__ __launch_bounds__(256) void getaffs_kernel(const float* __restrict__ seg,
                                                      float* __restrict__ out) {
    // Plane-per-XCD (linear NT write stream per XCD, fill-kernel pattern) with
    // ROTATED image walk: XCD k visits images k,k+1,...,k+7 (mod 8). At any
    // instant the 8 XCDs read 8 DIFFERENT images (each 4 MB, L2-resident on
    // its XCD) -> no cross-XCD duplicate-fetch herd (the R7 failure mode).
    const int bid = blockIdx.x;
    const int k     = bid & 7;                    // plane index == XCD
    const int local = bid >> 3;                   // 0..1023, linear plane walk
    const int b     = ((local >> 7) + k) & 7;     // rotated image index
    const int rg    = local & 127;                // row-group 0..127 (8 rows)
    const int j = threadIdx.x << 2;               // columns j..j+3

    const int ds[4] = {1, 3, 9, 27};
    const int d = ds[k >> 1];
    const bool is_row_off = (k & 1) == 0;         // even planes: (-d,0); odd: (0,-d)

    const float* img = seg + (size_t)b * HH * WW;
    float* outp = out + ((size_t)k * BB + b) * HH * WW;

    #pragma unroll
    for (int rr = 0; rr < 8; ++rr) {
        const int i = (rg << 3) + rr;
        const float* srow = img + (size_t)i * WW;
        const v4f c = *reinterpret_cast<const v4f*>(srow + j);
        v4f o;
        if (is_row_off) {
            v4f r;
            if (i >= d) {
                r = *reinterpret_cast<const v4f*>(srow - (size_t)d * WW + j);
            } else {
                r = (v4f){0.f, 0.f, 0.f, 0.f};
            }
            o.x = (r.x == c.x) ? 1.f : 0.f;
            o.y = (r.y == c.y) ? 1.f : 0.f;
            o.z = (r.z == c.z) ? 1.f : 0.f;
            o.w = (r.w == c.w) ? 1.f : 0.f;
        } else {
            if (j >= d) {
                const v4f s = *reinterpret_cast<const v4f*>(srow + (j - d));
                o.x = (s.x == c.x) ? 1.f : 0.f;
                o.y = (s.y == c.y) ? 1.f : 0.f;
                o.z = (s.z == c.z) ? 1.f : 0.f;
                o.w = (s.w == c.w) ? 1.f : 0.f;
            } else {
                #pragma unroll
                for (int t = 0; t < 4; ++t) {
                    const int col = j + t - d;
                    const float v = (col >= 0) ? srow[col] : 0.f;
                    o[t] = (v == c[t]) ? 1.f : 0.f;
                }
            }
        }
        __builtin_nontemporal_store(o, reinterpret_cast<v4f*>(outp + (size_t)i * WW + j));
    }
}

extern "C" void kernel_launch(void* const* d_in, const int* in_sizes, int n_in,
                              void* d_out, int out_size, void* d_ws, size_t ws_size,
                              hipStream_t stream) {
    const float* seg = (const float*)d_in[0];
    float* out = (float*)d_out;
    dim3 grid(8 * BB * (HH / 8));   // 8192: plane x (rotated image x row-group)
    dim3 block(WW / 4);
    getaffs_kernel<<<grid, block, 0, stream>>>(seg, out);
}

// Round 12
// 53.406 us; speedup vs baseline: 1.5962x; 1.5962x over previous
//
#include <hip/hip_runtime.h>

#define HH 1024
#define WW 1024
#define BB 8

typedef float v4f __attribute__((ext_vector_type(4)));

__global__ __launch_bounds__(256) void getaffs_kernel(const float* __restrict__ seg,
                                                      float* __restrict__ out) {
    // R3 winner (52.6 us, 5.47 TB/s effective on 288 MB mandatory traffic):
    // - image-per-XCD swizzle: bid&7 = XCD gets one contiguous 4 MB image ->
    //   all shifted-row reads L2-hit (beat identity mapping by 2.5 us).
    // - NT stores: 256 MB dead output bypasses L2 (beat plain stores by 24 us).
    // Falsified alternatives: plane-per-XCD linear write streams (85 us, R6/R7/
    // R10 incl. rotated reads), 4-row blocks with plane-outer stores (57 us).
    const int bid = blockIdx.x;
    const int row_id = ((bid & 7) << 10) + (bid >> 3);   // b*HH + i
    const int b = row_id >> 10;
    const int i = row_id & (HH - 1);
    const int j = threadIdx.x << 2;         // columns j..j+3

    const float* srow = seg + (size_t)row_id * WW;
    const v4f c = *reinterpret_cast<const v4f*>(srow + j);

    const size_t plane = (size_t)BB * HH * WW;       // elements per offset plane
    float* op = out + (size_t)row_id * WW + j;       // position inside a plane

    const int ds[4] = {1, 3, 9, 27};

    // Row offsets (-d, 0): output planes 0, 2, 4, 6 — aligned vector loads.
    #pragma unroll
    for (int k = 0; k < 4; ++k) {
        const int d = ds[k];
        v4f r;
        if (i - d >= 0) {
            r = *reinterpret_cast<const v4f*>(seg + ((size_t)b * HH + (i - d)) * WW + j);
        } else {
            r = (v4f){0.f, 0.f, 0.f, 0.f};
        }
        v4f o;
        o.x = (r.x == c.x) ? 1.f : 0.f;
        o.y = (r.y == c.y) ? 1.f : 0.f;
        o.z = (r.z == c.z) ? 1.f : 0.f;
        o.w = (r.w == c.w) ? 1.f : 0.f;
        __builtin_nontemporal_store(o, reinterpret_cast<v4f*>(op + (size_t)(2 * k) * plane));
    }

    // Col offsets (0, -d): output planes 1, 3, 5, 7 — one 4B-aligned vector
    // load covers cols j-d..j+3-d; guarded scalar fallback only for j < d
    // (lanes 0..6 of wave 0).
    #pragma unroll
    for (int k = 0; k < 4; ++k) {
        const int d = ds[k];
        v4f o;
        if (j >= d) {
            const v4f s = *reinterpret_cast<const v4f*>(srow + (j - d));
            o.x = (s.x == c.x) ? 1.f : 0.f;
            o.y = (s.y == c.y) ? 1.f : 0.f;
            o.z = (s.z == c.z) ? 1.f : 0.f;
            o.w = (s.w == c.w) ? 1.f : 0.f;
        } else {
            #pragma unroll
            for (int t = 0; t < 4; ++t) {
                const int col = j + t - d;
                const float v = (col >= 0) ? srow[col] : 0.f;
                o[t] = (v == c[t]) ? 1.f : 0.f;
            }
        }
        __builtin_nontemporal_store(o, reinterpret_cast<v4f*>(op + (size_t)(2 * k + 1) * plane));
    }
}

extern "C" void kernel_launch(void* const* d_in, const int* in_sizes, int n_in,
                              void* d_out, int out_size, void* d_ws, size_t ws_size,
                              hipStream_t stream) {
    const float* seg = (const float*)d_in[0];
    float* out = (float*)d_out;
    dim3 grid(BB * HH);
    dim3 block(WW / 4);
    getaffs_kernel<<<grid, block, 0, stream>>>(seg, out);
}